// Round 4
// baseline (384.045 us; speedup 1.0000x reference)
//
#include <hip/hip_runtime.h>

// Problem constants (match reference)
#define NB 8
#define HH 352
#define WW 352
#define TX 32
#define TY 32
#define HALO_L 7                 // left/right halo 7: mask(q at +-5) needs sal +-7
#define HALO_T 2                 // taps never look up; top halo 2 only for mask window
#define LW 46                    // 7 + 32 + 7
#define LH 41                    // 2 + 32 + 7
#define LSTRIDE 47               // float4 units, odd -> banks spread
#define MW 42                    // mask plane cols: gx in [x0-5, x0+36]
#define MH 37                    // mask plane rows: gy in [y0, y0+36]
#define MSTRIDE 44               // float units, mult of 4 for b128 reads
#define SSTRIDE 48               // sal plane stride (floats)
#define TILES_X 11
#define TILES_Y 11
#define NBLK (TILES_X * TILES_Y * NB)   // 968

// Pre-scale rgb by sqrt(ALPHA * log2(e)) so wgt = exp2(-sum(d^2))
#define RGB_SCALE 16.98644781888824f

typedef float f32x2 __attribute__((ext_vector_type(2)));

__device__ __forceinline__ float elem(float4 q, int c) {
    return c == 0 ? q.x : c == 1 ? q.y : c == 2 ? q.z : q.w;
}

// One window float4 vs a PAIR of pre-negated packed centers, with mask-weight mq
// (mq = mask of the shared window pixel q). Computes v = e*|ds| per tap;
// accP += v (m_p applied after the loop); accQ += v*mq.
__device__ __forceinline__ void tap_pair(const float4& w, float mq,
                                         f32x2 ncx, f32x2 ncy, f32x2 ncz, f32x2 ncw,
                                         f32x2& accP, f32x2& accQ) {
    f32x2 d0 = ncx + w.x;        // pk_add, scalar broadcast
    f32x2 d1 = ncy + w.y;
    f32x2 d2 = ncz + w.z;
    f32x2 s  = d0 * d0;
    s += d1 * d1;                // pk_fma
    s += d2 * d2;
    f32x2 ds = ncw + w.w;
    f32x2 v;
    v.x = __builtin_amdgcn_exp2f(-s.x) * fabsf(ds.x);  // abs folds as VOP3 modifier
    v.y = __builtin_amdgcn_exp2f(-s.y) * fabsf(ds.y);
    accP += v;                   // pk_add
    f32x2 mqv; mqv.x = mq; mqv.y = mq;
    accQ += v * mqv;             // pk_fma
}

__device__ __forceinline__ void tap_scalar(const float4& w, float mq,
                                           float ncx, float ncy, float ncz, float ncw,
                                           float& aP, float& aQ) {
    float d0 = w.x + ncx, d1 = w.y + ncy, d2 = w.z + ncz;
    float s = fmaf(d0, d0, fmaf(d1, d1, d2 * d2));
    float v = __builtin_amdgcn_exp2f(-s) * fabsf(w.w + ncw);
    aP += v;
    aQ = fmaf(v, mq, aQ);
}

// Cooperative mask plane: m(q) for q rows [y0, y0+37), cols [x0-5, x0+37).
// dil = max(5x5 sal) > 0.5 (zero-pads harmless for max); ero = min over VALID > 0.5.
template <bool INTERIOR>
__device__ __forceinline__ void mask_plane_fn(const float* __restrict__ salp,
                                              float* __restrict__ maskp,
                                              int y0, int x0, int t) {
    for (int i = t; i < MH * MW; i += 256) {
        int mr = i / MW, mc = i - mr * MW;
        int gy = y0 + mr, gx = x0 - 5 + mc;
        float m = 0.f;
        if (INTERIOR || (gy < HH && (unsigned)gx < (unsigned)WW)) {
            float mx = 0.f, mn = 1.f;
            #pragma unroll
            for (int r = 0; r < 5; ++r) {
                bool rowv = INTERIOR || ((unsigned)(gy - 2 + r) < (unsigned)HH);
                const float* sr = &salp[(mr + r) * SSTRIDE + mc];
                #pragma unroll
                for (int c = 0; c < 5; ++c) {
                    float sv = sr[c];
                    mx = fmaxf(mx, sv);
                    bool ok = INTERIOR || (rowv && ((unsigned)(gx - 2 + c) < (unsigned)WW));
                    mn = fminf(mn, ok ? sv : 1.f);
                }
            }
            m = (mx > 0.5f ? 1.f : 0.f) - (mn > 0.5f ? 1.f : 0.f);
        }
        maskp[mr * MSTRIDE + mc] = m;
    }
}

__global__ __launch_bounds__(256, 2)
void btm_loss_kernel(const float* __restrict__ pred,
                     const float* __restrict__ feat,
                     float2* __restrict__ partials) {
    __shared__ __align__(16) float4 tile[LH * LSTRIDE];   // 30.8 KB AoS (r,g,b,sal)
    __shared__ __align__(16) float  salp[LH * SSTRIDE];   // 7.9 KB sal-only (mask pass)
    __shared__ __align__(16) float  maskp[MH * MSTRIDE];  // 6.5 KB mask plane
    __shared__ float2 wred[4];

    const int bid = blockIdx.x;
    const int tx_blk = bid % TILES_X;
    const int ty_blk = (bid / TILES_X) % TILES_Y;
    const int n = bid / (TILES_X * TILES_Y);
    const int x0 = tx_blk * TX;
    const int y0 = ty_blk * TY;

    const size_t plane = (size_t)HH * WW;
    const float* fr = feat + ((size_t)n * 3 + 0) * plane;
    const float* fg = feat + ((size_t)n * 3 + 1) * plane;
    const float* fb = feat + ((size_t)n * 3 + 2) * plane;
    const float* ps = pred + (size_t)n * plane;

    // ---- stage tile (zero-padded halo, matching jnp.pad; rgb pre-scaled) ----
    for (int i = threadIdx.x; i < LH * LW; i += 256) {
        int lr = i / LW;
        int lc = i - lr * LW;
        int gy = y0 + lr - HALO_T;
        int gx = x0 + lc - HALO_L;
        float4 v = make_float4(0.f, 0.f, 0.f, 0.f);
        if ((unsigned)gy < (unsigned)HH && (unsigned)gx < (unsigned)WW) {
            int gi = gy * WW + gx;
            v.x = fr[gi] * RGB_SCALE;
            v.y = fg[gi] * RGB_SCALE;
            v.z = fb[gi] * RGB_SCALE;
            v.w = ps[gi];
        }
        tile[lr * LSTRIDE + lc] = v;
        salp[lr * SSTRIDE + lc] = v.w;
    }
    __syncthreads();

    // ---- cooperative mask plane ----
    const bool interior = (tx_blk >= 1) && (tx_blk <= TILES_X - 2) &&
                          (ty_blk >= 1) && (ty_blk <= TILES_Y - 2);
    if (interior) mask_plane_fn<true >(salp, maskp, y0, x0, threadIdx.x);
    else          mask_plane_fn<false>(salp, maskp, y0, x0, threadIdx.x);
    __syncthreads();

    // ---- half-window pair taps: each thread owns 4 x-adjacent pixels ----
    const int t   = threadIdx.x;
    const int txq = t & 7;       // 0..7
    const int ty  = t >> 3;      // 0..31
    const int px0 = txq * 4;

    // trow[dy*LSTRIDE + c] = tile col (px0+c) of window row dy (tile row ty+2+dy)
    const float4* trow = tile + (ty + HALO_T) * LSTRIDE + px0;
    const float*  mrow = maskp + ty * MSTRIDE + px0;   // mask row of p, col px0-5 rel gx

    float4 c0 = trow[7], c1 = trow[8], c2 = trow[9], c3 = trow[10];
    f32x2 n01x = {-c0.x, -c1.x}, n01y = {-c0.y, -c1.y}, n01z = {-c0.z, -c1.z}, n01w = {-c0.w, -c1.w};
    f32x2 n23x = {-c2.x, -c3.x}, n23y = {-c2.y, -c3.y}, n23z = {-c2.z, -c3.z}, n23w = {-c2.w, -c3.w};

    f32x2 aP01 = {0.f, 0.f}, aP23 = {0.f, 0.f};
    f32x2 aQ01 = {0.f, 0.f}, aQ23 = {0.f, 0.f};
    float sP0 = 0.f, sP1 = 0.f, sP2 = 0.f, sP3 = 0.f, sQ = 0.f;

    // dy = 0 row: pairs to the RIGHT only (dx 1..5). Window cols px0+8..px0+15.
    // mf0 caches mask cols px0+4..px0+15; also supplies m_p (cols px0+5..px0+8).
    float4 w0[8];
    #pragma unroll
    for (int j = 0; j < 8; ++j) w0[j] = trow[8 + j];
    float4 mf0[3];
    #pragma unroll
    for (int q = 0; q < 3; ++q) mf0[q] = *(const float4*)&mrow[4 + 4 * q];

    tap_scalar(w0[0], elem(mf0[0], 2), n01x.x, n01y.x, n01z.x, n01w.x, sP0, sQ); // c0 dx=1
    #pragma unroll
    for (int j = 1; j <= 4; ++j)  // c0 dx 2..5 / c1 dx 1..4
        tap_pair(w0[j], elem(mf0[(j + 2) >> 2], (j + 2) & 3), n01x, n01y, n01z, n01w, aP01, aQ01);
    tap_scalar(w0[5], elem(mf0[1], 3), n01x.y, n01y.y, n01z.y, n01w.y, sP1, sQ); // c1 dx=5
    tap_scalar(w0[2], elem(mf0[1], 0), n23x.x, n23y.x, n23z.x, n23w.x, sP2, sQ); // c2 dx=1
    #pragma unroll
    for (int j = 3; j <= 6; ++j)  // c2 dx 2..5 / c3 dx 1..4
        tap_pair(w0[j], elem(mf0[(j + 2) >> 2], (j + 2) & 3), n23x, n23y, n23z, n23w, aP23, aQ23);
    tap_scalar(w0[7], elem(mf0[2], 1), n23x.y, n23y.y, n23z.y, n23w.y, sP3, sQ); // c3 dx=5

    // dy = 1..5 rows: full dx range [-5,5]. Window cols px0+2..px0+15 (14 b128).
    #pragma unroll
    for (int dy = 1; dy <= 5; ++dy) {
        float4 w[14];
        #pragma unroll
        for (int j = 0; j < 14; ++j) w[j] = trow[dy * LSTRIDE + 2 + j];
        float4 mf[4];
        const float* mro = mrow + dy * MSTRIDE;
        #pragma unroll
        for (int q = 0; q < 4; ++q) mf[q] = *(const float4*)&mro[4 * q];

        tap_scalar(w[0], elem(mf[0], 0), n01x.x, n01y.x, n01z.x, n01w.x, sP0, sQ); // c0 dx=-5
        #pragma unroll
        for (int j = 1; j <= 10; ++j)
            tap_pair(w[j], elem(mf[j >> 2], j & 3), n01x, n01y, n01z, n01w, aP01, aQ01);
        tap_scalar(w[11], elem(mf[2], 3), n01x.y, n01y.y, n01z.y, n01w.y, sP1, sQ); // c1 dx=+5
        tap_scalar(w[2],  elem(mf[0], 2), n23x.x, n23y.x, n23z.x, n23w.x, sP2, sQ); // c2 dx=-5
        #pragma unroll
        for (int j = 3; j <= 12; ++j)
            tap_pair(w[j], elem(mf[j >> 2], j & 3), n23x, n23y, n23z, n23w, aP23, aQ23);
        tap_scalar(w[13], elem(mf[3], 1), n23x.y, n23y.y, n23z.y, n23w.y, sP3, sQ); // c3 dx=+5
    }

    // ---- combine: num = sum_i m_i*(A_H(i) + pad_i) + sum(v*m_q) ----
    float m0 = mf0[0].y, m1 = mf0[0].z, m2 = mf0[0].w, m3 = mf0[1].x;
    float e0 = aP01.x + sP0, e1 = aP01.y + sP1;
    float e2 = aP23.x + sP2, e3 = aP23.y + sP3;

    // Upper/left pad taps (closed form): all pads identical for a pixel.
    const bool padblk = (ty_blk == 0) || (tx_blk == 0) || (tx_blk == TILES_X - 1);
    if (padblk) {
        const int gy = y0 + ty;
        const int nneg = (5 - gy) > 0 ? (5 - gy) : 0;   // # fully-pad rows above
        #pragma unroll
        for (int i = 0; i < 4; ++i) {
            const int gx = x0 + px0 + i;
            const int cl = (5 - gx) > 0 ? (5 - gx) : 0;
            const int cr = (gx - 346) > 0 ? (gx - 346) : 0;
            const int np = nneg * 11 + (5 - nneg) * (cl + cr) + cl;
            if (np > 0) {
                float4 ci = (i == 0) ? c0 : (i == 1) ? c1 : (i == 2) ? c2 : c3;
                float s2 = fmaf(ci.x, ci.x, fmaf(ci.y, ci.y, ci.z * ci.z));
                float vp = __builtin_amdgcn_exp2f(-s2) * ci.w * (float)np;
                if (i == 0) e0 += vp; else if (i == 1) e1 += vp;
                else if (i == 2) e2 += vp; else e3 += vp;
            }
        }
    }

    float num = fmaf(m0, e0, fmaf(m1, e1, fmaf(m2, e2, m3 * e3)))
              + ((aQ01.x + aQ01.y) + (aQ23.x + aQ23.y)) + sQ;
    float den = (m0 + m1) + (m2 + m3);

    // ---- wave reduce -> block reduce -> deterministic partial store ----
    #pragma unroll
    for (int off = 32; off > 0; off >>= 1) {
        num += __shfl_down(num, off, 64);
        den += __shfl_down(den, off, 64);
    }
    const int wid  = t >> 6;
    const int lane = t & 63;
    if (lane == 0) wred[wid] = make_float2(num, den);
    __syncthreads();
    if (t == 0) {
        float2 a = wred[0];
        #pragma unroll
        for (int w2 = 1; w2 < 4; ++w2) { a.x += wred[w2].x; a.y += wred[w2].y; }
        partials[bid] = a;
    }
}

__global__ __launch_bounds__(256)
void btm_finalize_kernel(const float2* __restrict__ partials,
                         float* __restrict__ out) {
    __shared__ float2 wred[4];
    float num = 0.f, den = 0.f;
    for (int i = threadIdx.x; i < NBLK; i += 256) {
        float2 p = partials[i];
        num += p.x;
        den += p.y;
    }
    #pragma unroll
    for (int off = 32; off > 0; off >>= 1) {
        num += __shfl_down(num, off, 64);
        den += __shfl_down(den, off, 64);
    }
    int wid  = threadIdx.x >> 6;
    int lane = threadIdx.x & 63;
    if (lane == 0) wred[wid] = make_float2(num, den);
    __syncthreads();
    if (threadIdx.x == 0) {
        float2 a = wred[0];
        #pragma unroll
        for (int w = 1; w < 4; ++w) { a.x += wred[w].x; a.y += wred[w].y; }
        out[0] = a.x / (a.y + 1e-6f);
    }
}

extern "C" void kernel_launch(void* const* d_in, const int* in_sizes, int n_in,
                              void* d_out, int out_size, void* d_ws, size_t ws_size,
                              hipStream_t stream) {
    const float* pred = (const float*)d_in[0];  // (8,1,352,352) fp32
    const float* feat = (const float*)d_in[1];  // (8,3,352,352) fp32
    float* out = (float*)d_out;                 // scalar fp32
    float2* partials = (float2*)d_ws;           // NBLK float2 = 7.7 KB

    btm_loss_kernel<<<dim3(NBLK), dim3(256), 0, stream>>>(pred, feat, partials);
    btm_finalize_kernel<<<dim3(1), dim3(256), 0, stream>>>(partials, out);
}

// Round 5
// 95.690 us; speedup vs baseline: 4.0134x; 4.0134x over previous
//
#include <hip/hip_runtime.h>

// Problem constants (match reference)
#define NB 8
#define HH 352
#define WW 352
#define TX 32
#define TY 32
#define HALO_L 7                 // left/right halo 7: mask(q at +-5) needs sal +-7
#define HALO_T 2                 // taps never look up; top halo 2 only for mask window
#define LW 46                    // 7 + 32 + 7
#define LH 41                    // 2 + 32 + 7
#define LSTRIDE 47               // float4 units, odd -> banks spread
#define MW 42                    // mask plane cols: gx in [x0-5, x0+36]
#define MH 37                    // mask plane rows: gy in [y0, y0+36]
#define MSTRIDE 44               // float units, mult of 4 for b128 reads
#define SSTRIDE 48               // sal plane stride (floats)
#define TILES_X 11
#define TILES_Y 11
#define NBLK (TILES_X * TILES_Y * NB)   // 968

// Pre-scale rgb by sqrt(ALPHA * log2(e)) so wgt = exp2(-sum(d^2))
#define RGB_SCALE 16.98644781888824f

typedef float f32x2 __attribute__((ext_vector_type(2)));

__device__ __forceinline__ float elem(float4 q, int c) {
    return c == 0 ? q.x : c == 1 ? q.y : c == 2 ? q.z : q.w;
}

// One window float4 vs a PAIR of pre-negated packed centers, with mask-weight mq
// (mq = mask of the shared window pixel q). v = e*|ds| per tap;
// accP += v (m_p applied after the loop); accQ += v*mq.
__device__ __forceinline__ void tap_pair(const float4& w, float mq,
                                         f32x2 ncx, f32x2 ncy, f32x2 ncz, f32x2 ncw,
                                         f32x2& accP, f32x2& accQ) {
    f32x2 d0 = ncx + w.x;        // pk_add, scalar broadcast
    f32x2 d1 = ncy + w.y;
    f32x2 d2 = ncz + w.z;
    f32x2 s  = d0 * d0;
    s += d1 * d1;                // pk_fma
    s += d2 * d2;
    f32x2 ds = ncw + w.w;
    f32x2 v;
    v.x = __builtin_amdgcn_exp2f(-s.x) * fabsf(ds.x);  // abs folds as VOP3 modifier
    v.y = __builtin_amdgcn_exp2f(-s.y) * fabsf(ds.y);
    accP += v;                   // pk_add
    f32x2 mqv; mqv.x = mq; mqv.y = mq;
    accQ += v * mqv;             // pk_fma
}

__device__ __forceinline__ void tap_scalar(const float4& w, float mq,
                                           float ncx, float ncy, float ncz, float ncw,
                                           float& aP, float& aQ) {
    float d0 = w.x + ncx, d1 = w.y + ncy, d2 = w.z + ncz;
    float s = fmaf(d0, d0, fmaf(d1, d1, d2 * d2));
    float v = __builtin_amdgcn_exp2f(-s) * fabsf(w.w + ncw);
    aP += v;
    aQ = fmaf(v, mq, aQ);
}

// Cooperative mask plane: m(q) for q rows [y0, y0+37), cols [x0-5, x0+37).
// dil = max(5x5 sal) > 0.5 (zero-pads harmless for max); ero = min over VALID > 0.5.
template <bool INTERIOR>
__device__ __forceinline__ void mask_plane_fn(const float* __restrict__ salp,
                                              float* __restrict__ maskp,
                                              int y0, int x0, int t) {
    for (int i = t; i < MH * MW; i += 256) {
        int mr = i / MW, mc = i - mr * MW;
        int gy = y0 + mr, gx = x0 - 5 + mc;
        float m = 0.f;
        if (INTERIOR || (gy < HH && (unsigned)gx < (unsigned)WW)) {
            float mx = 0.f, mn = 1.f;
            #pragma unroll
            for (int r = 0; r < 5; ++r) {
                bool rowv = INTERIOR || ((unsigned)(gy - 2 + r) < (unsigned)HH);
                const float* sr = &salp[(mr + r) * SSTRIDE + mc];
                #pragma unroll
                for (int c = 0; c < 5; ++c) {
                    float sv = sr[c];
                    mx = fmaxf(mx, sv);
                    bool ok = INTERIOR || (rowv && ((unsigned)(gx - 2 + c) < (unsigned)WW));
                    mn = fminf(mn, ok ? sv : 1.f);
                }
            }
            m = (mx > 0.5f ? 1.f : 0.f) - (mn > 0.5f ? 1.f : 0.f);
        }
        maskp[mr * MSTRIDE + mc] = m;
    }
}

__global__ __launch_bounds__(256, 2)
void btm_loss_kernel(const float* __restrict__ pred,
                     const float* __restrict__ feat,
                     float2* __restrict__ partials) {
    __shared__ __align__(16) float4 tile[LH * LSTRIDE];   // 30.8 KB AoS (r,g,b,sal)
    __shared__ __align__(16) float  salp[LH * SSTRIDE];   // 7.9 KB sal-only (mask pass)
    __shared__ __align__(16) float  maskp[MH * MSTRIDE];  // 6.5 KB mask plane
    __shared__ float2 wred[4];

    const int bid = blockIdx.x;
    const int tx_blk = bid % TILES_X;
    const int ty_blk = (bid / TILES_X) % TILES_Y;
    const int n = bid / (TILES_X * TILES_Y);
    const int x0 = tx_blk * TX;
    const int y0 = ty_blk * TY;

    const size_t plane = (size_t)HH * WW;
    const float* fr = feat + ((size_t)n * 3 + 0) * plane;
    const float* fg = feat + ((size_t)n * 3 + 1) * plane;
    const float* fb = feat + ((size_t)n * 3 + 2) * plane;
    const float* ps = pred + (size_t)n * plane;

    // ---- stage tile (zero-padded halo, matching jnp.pad; rgb pre-scaled) ----
    for (int i = threadIdx.x; i < LH * LW; i += 256) {
        int lr = i / LW;
        int lc = i - lr * LW;
        int gy = y0 + lr - HALO_T;
        int gx = x0 + lc - HALO_L;
        float4 v = make_float4(0.f, 0.f, 0.f, 0.f);
        if ((unsigned)gy < (unsigned)HH && (unsigned)gx < (unsigned)WW) {
            int gi = gy * WW + gx;
            v.x = fr[gi] * RGB_SCALE;
            v.y = fg[gi] * RGB_SCALE;
            v.z = fb[gi] * RGB_SCALE;
            v.w = ps[gi];
        }
        tile[lr * LSTRIDE + lc] = v;
        salp[lr * SSTRIDE + lc] = v.w;
    }
    __syncthreads();

    // ---- cooperative mask plane ----
    const bool interior = (tx_blk >= 1) && (tx_blk <= TILES_X - 2) &&
                          (ty_blk >= 1) && (ty_blk <= TILES_Y - 2);
    if (interior) mask_plane_fn<true >(salp, maskp, y0, x0, threadIdx.x);
    else          mask_plane_fn<false>(salp, maskp, y0, x0, threadIdx.x);
    __syncthreads();

    // ---- half-window pair taps: each thread owns 4 x-adjacent pixels ----
    const int t   = threadIdx.x;
    const int txq = t & 7;       // 0..7
    const int ty  = t >> 3;      // 0..31
    const int px0 = txq * 4;

    // trow[dy*LSTRIDE + c] = tile col (px0+c) of window row dy (tile row ty+2+dy)
    const float4* trow = tile + (ty + HALO_T) * LSTRIDE + px0;
    const float*  mrow = maskp + ty * MSTRIDE + px0;   // mask row of p, col px0-5 rel gx

    float4 c0 = trow[7], c1 = trow[8], c2 = trow[9], c3 = trow[10];
    f32x2 n01x = {-c0.x, -c1.x}, n01y = {-c0.y, -c1.y}, n01z = {-c0.z, -c1.z}, n01w = {-c0.w, -c1.w};
    f32x2 n23x = {-c2.x, -c3.x}, n23y = {-c2.y, -c3.y}, n23z = {-c2.z, -c3.z}, n23w = {-c2.w, -c3.w};

    f32x2 aP01 = {0.f, 0.f}, aP23 = {0.f, 0.f};
    f32x2 aQ01 = {0.f, 0.f}, aQ23 = {0.f, 0.f};
    float sP0 = 0.f, sP1 = 0.f, sP2 = 0.f, sP3 = 0.f, sQ = 0.f;

    // dy = 0 row: pairs to the RIGHT only (dx 1..5). Window cols px0+8..px0+15.
    // mf0 caches mask cols px0+4..px0+15; also supplies m_p (cols px0+5..px0+8).
    float4 mf0[3];
    #pragma unroll
    for (int q = 0; q < 3; ++q) mf0[q] = *(const float4*)&mrow[4 + 4 * q];
    {
        float4 w0[8];
        #pragma unroll
        for (int j = 0; j < 8; ++j) w0[j] = trow[8 + j];

        tap_scalar(w0[0], elem(mf0[0], 2), n01x.x, n01y.x, n01z.x, n01w.x, sP0, sQ); // c0 dx=1
        #pragma unroll
        for (int j = 1; j <= 4; ++j)  // c0 dx 2..5 / c1 dx 1..4
            tap_pair(w0[j], elem(mf0[(j + 2) >> 2], (j + 2) & 3), n01x, n01y, n01z, n01w, aP01, aQ01);
        tap_scalar(w0[5], elem(mf0[1], 3), n01x.y, n01y.y, n01z.y, n01w.y, sP1, sQ); // c1 dx=5
        tap_scalar(w0[2], elem(mf0[1], 0), n23x.x, n23y.x, n23z.x, n23w.x, sP2, sQ); // c2 dx=1
        #pragma unroll
        for (int j = 3; j <= 6; ++j)  // c2 dx 2..5 / c3 dx 1..4
            tap_pair(w0[j], elem(mf0[(j + 2) >> 2], (j + 2) & 3), n23x, n23y, n23z, n23w, aP23, aQ23);
        tap_scalar(w0[7], elem(mf0[2], 1), n23x.y, n23y.y, n23z.y, n23w.y, sP3, sQ); // c3 dx=5
    }

    // dy = 1..5 rows: full dx range [-5,5]. Window cols px0+2..px0+15 (14 b128).
    // KEEP THIS LOOP ROLLED (unroll 1): R4's full unroll hoisted ~70 float4 LDS
    // loads -> 280+ VGPR liveness -> scratch spill (WRITE_SIZE 565 MB, 8x slower).
    // Rolled, the compiler JIT-sinks ds_read_b128 with small liveness (R0/R3 regime).
    #pragma unroll 1
    for (int dy = 1; dy <= 5; ++dy) {
        float4 w[14];
        #pragma unroll
        for (int j = 0; j < 14; ++j) w[j] = trow[dy * LSTRIDE + 2 + j];
        float4 mf[4];
        const float* mro = mrow + dy * MSTRIDE;
        #pragma unroll
        for (int q = 0; q < 4; ++q) mf[q] = *(const float4*)&mro[4 * q];

        tap_scalar(w[0], elem(mf[0], 0), n01x.x, n01y.x, n01z.x, n01w.x, sP0, sQ); // c0 dx=-5
        #pragma unroll
        for (int j = 1; j <= 10; ++j)
            tap_pair(w[j], elem(mf[j >> 2], j & 3), n01x, n01y, n01z, n01w, aP01, aQ01);
        tap_scalar(w[11], elem(mf[2], 3), n01x.y, n01y.y, n01z.y, n01w.y, sP1, sQ); // c1 dx=+5
        tap_scalar(w[2],  elem(mf[0], 2), n23x.x, n23y.x, n23z.x, n23w.x, sP2, sQ); // c2 dx=-5
        #pragma unroll
        for (int j = 3; j <= 12; ++j)
            tap_pair(w[j], elem(mf[j >> 2], j & 3), n23x, n23y, n23z, n23w, aP23, aQ23);
        tap_scalar(w[13], elem(mf[3], 1), n23x.y, n23y.y, n23z.y, n23w.y, sP3, sQ); // c3 dx=+5
    }

    // ---- combine: num = sum_i m_i*(A_H(i) + pad_i) + sum(v*m_q) ----
    float m0 = mf0[0].y, m1 = mf0[0].z, m2 = mf0[0].w, m3 = mf0[1].x;
    float e0 = aP01.x + sP0, e1 = aP01.y + sP1;
    float e2 = aP23.x + sP2, e3 = aP23.y + sP3;

    // Upper/left pad taps (closed form): all pads identical for a pixel.
    const bool padblk = (ty_blk == 0) || (tx_blk == 0) || (tx_blk == TILES_X - 1);
    if (padblk) {
        const int gy = y0 + ty;
        const int nneg = (5 - gy) > 0 ? (5 - gy) : 0;   // # fully-pad rows above
        #pragma unroll
        for (int i = 0; i < 4; ++i) {
            const int gx = x0 + px0 + i;
            const int cl = (5 - gx) > 0 ? (5 - gx) : 0;
            const int cr = (gx - 346) > 0 ? (gx - 346) : 0;
            const int np = nneg * 11 + (5 - nneg) * (cl + cr) + cl;
            if (np > 0) {
                float4 ci = (i == 0) ? c0 : (i == 1) ? c1 : (i == 2) ? c2 : c3;
                float s2 = fmaf(ci.x, ci.x, fmaf(ci.y, ci.y, ci.z * ci.z));
                float vp = __builtin_amdgcn_exp2f(-s2) * ci.w * (float)np;
                if (i == 0) e0 += vp; else if (i == 1) e1 += vp;
                else if (i == 2) e2 += vp; else e3 += vp;
            }
        }
    }

    float num = fmaf(m0, e0, fmaf(m1, e1, fmaf(m2, e2, m3 * e3)))
              + ((aQ01.x + aQ01.y) + (aQ23.x + aQ23.y)) + sQ;
    float den = (m0 + m1) + (m2 + m3);

    // ---- wave reduce -> block reduce -> deterministic partial store ----
    #pragma unroll
    for (int off = 32; off > 0; off >>= 1) {
        num += __shfl_down(num, off, 64);
        den += __shfl_down(den, off, 64);
    }
    const int wid  = t >> 6;
    const int lane = t & 63;
    if (lane == 0) wred[wid] = make_float2(num, den);
    __syncthreads();
    if (t == 0) {
        float2 a = wred[0];
        #pragma unroll
        for (int w2 = 1; w2 < 4; ++w2) { a.x += wred[w2].x; a.y += wred[w2].y; }
        partials[bid] = a;
    }
}

__global__ __launch_bounds__(256)
void btm_finalize_kernel(const float2* __restrict__ partials,
                         float* __restrict__ out) {
    __shared__ float2 wred[4];
    float num = 0.f, den = 0.f;
    for (int i = threadIdx.x; i < NBLK; i += 256) {
        float2 p = partials[i];
        num += p.x;
        den += p.y;
    }
    #pragma unroll
    for (int off = 32; off > 0; off >>= 1) {
        num += __shfl_down(num, off, 64);
        den += __shfl_down(den, off, 64);
    }
    int wid  = threadIdx.x >> 6;
    int lane = threadIdx.x & 63;
    if (lane == 0) wred[wid] = make_float2(num, den);
    __syncthreads();
    if (threadIdx.x == 0) {
        float2 a = wred[0];
        #pragma unroll
        for (int w = 1; w < 4; ++w) { a.x += wred[w].x; a.y += wred[w].y; }
        out[0] = a.x / (a.y + 1e-6f);
    }
}

extern "C" void kernel_launch(void* const* d_in, const int* in_sizes, int n_in,
                              void* d_out, int out_size, void* d_ws, size_t ws_size,
                              hipStream_t stream) {
    const float* pred = (const float*)d_in[0];  // (8,1,352,352) fp32
    const float* feat = (const float*)d_in[1];  // (8,3,352,352) fp32
    float* out = (float*)d_out;                 // scalar fp32
    float2* partials = (float2*)d_ws;           // NBLK float2 = 7.7 KB

    btm_loss_kernel<<<dim3(NBLK), dim3(256), 0, stream>>>(pred, feat, partials);
    btm_finalize_kernel<<<dim3(1), dim3(256), 0, stream>>>(partials, out);
}